// Round 5
// baseline (1529.737 us; speedup 1.0000x reference)
//
#include <hip/hip_runtime.h>

#define L_ 2
#define T_ 512
#define B_ 128
#define F_ 4
#define H_ 256
#define QSIGN_MASK 0x5390

typedef __attribute__((ext_vector_type(8))) short short8;
typedef __attribute__((ext_vector_type(4))) float f32x4;

// Mailbox: layer-0 normalized output, bf16x4 packed per (t,b); norm-1 => nonzero.
__device__ unsigned long long g_inter_q[T_][B_];

__global__ void zero_inter() {
  ((unsigned long long*)g_inter_q)[blockIdx.x * 256 + threadIdx.x] = 0ull;
}

__device__ __forceinline__ unsigned f2bf(float f) {
  unsigned u = __float_as_uint(f);
  return (u + 0x7fff + ((u >> 16) & 1)) >> 16;
}
__device__ __forceinline__ float fast_sigmoid(float x) { return 1.f / (1.f + __expf(-x)); }
__device__ __forceinline__ float fast_tanh(float x) {
  float a = fabsf(x), e = __expf(2.f * a);
  return copysignf(1.f - 2.f / (e + 1.f), x);
}

union FragU { short8 v; uint4 u; unsigned w[4]; };

// Raw workgroup barrier: drains LDS ops only; global loads/stores stay in flight.
#define BAR() do { \
  __builtin_amdgcn_sched_barrier(0); \
  asm volatile("s_waitcnt lgkmcnt(0)" ::: "memory"); \
  __builtin_amdgcn_s_barrier(); \
  __builtin_amdgcn_sched_barrier(0); \
} while (0)

// Grid = 32 WGs x 512 threads (8 waves = 2 per SIMD: cross-wave stall hiding).
// R4 ERRATum: __launch_bounds__(512,2) made the compiler cap VGPR at 128 ->
// the 208-reg working set (Bf[32] alone is 128 VGPRs) spilled to scratch
// (WRITE_SIZE 1MB->11.6MB) and the experiment measured spill latency, not TLP.
// This round: __launch_bounds__(512,1) -> compiler free to allocate ~208-230
// (R3's per-wave stream allocated 208); at <=256 VGPRs the HW co-resides
// 2 waves/SIMD (2x230 <= 512-reg file), which is the actual TLP experiment.
// blockIdx<16: layer-0 producer (8 batches each); else layer-1 consumer.
// Wave w: M-block mblk=w>>2 (batches mblk*4..+3), cols u in [16*(w&3), +16).
// Per wave per step: 36 MFMA (16x16x32), in-lane gates, dual +/-h LDS copies
// (signs baked into read offsets), bias via MFMA C-operand, cvt_pk h-pack.
// Duties (all cross-step handoffs, on 3 different SIMDs):
//   wave1: staging — builds x/mailbox A-frag words into sh_ax entry s+3 at
//          step s (lanes 0-31 cover both M-blocks); issues load for s+4.
//   wave2: proj ks 0-3 of h[s-1] into regs (C-op carries fc bias); at step s
//          publishes entry s-2 = norm(preg + wave7's partial from step s-1).
//   wave7: proj ks 4-7 of h[s-1] -> sh_pp[s&1] (read by wave2 at s+1).
__launch_bounds__(512, 1)
__global__ void qlstm_fused(const float* __restrict__ x_in,
                            const float* __restrict__ uhr, const float* __restrict__ uhi,
                            const float* __restrict__ uhj, const float* __restrict__ uhk,
                            const float* __restrict__ wxr, const float* __restrict__ wxi,
                            const float* __restrict__ wxj, const float* __restrict__ wxk,
                            const float* __restrict__ wxb_all,
                            const float* __restrict__ fcw_all, const float* __restrict__ fcb_all,
                            float* __restrict__ out_final)
{
  // [buf][copy: 0=+h 1=-h][bat 0..7][272 shorts]; strides (B): buf 8704, copy 4352, bat 544
  __shared__ __align__(16) unsigned short sh_h[2][2][8][272];
  __shared__ __align__(16) unsigned sh_ax[4][2][64][4];  // [slot][mblk][lane][4w] Ax frags
  __shared__ __align__(16) float sh_pp[2][8][4];         // [par][batch][f] proj partial

  const int t     = threadIdx.x;
  const int role  = blockIdx.x >> 4;
  const int bg    = blockIdx.x & 15;
  const int bg0   = bg * 8;
  const int layer = role;
  const int wv    = t >> 6;
  const int lane  = t & 63;
  const int quad  = lane >> 4;
  const int sub   = lane & 15;
  const int mblk  = wv >> 2;      // M-block: batches mblk*4 .. mblk*4+3
  const int cb    = wv & 3;       // column block

  const float* wb = wxb_all + layer * 4 * H_;
  const float* fw = fcw_all + layer * H_ * F_;
  const float* fb = fcb_all + layer * F_;

  for (int i = t; i < 8704; i += 512) ((unsigned short*)sh_h)[i] = 0;
  for (int i = t; i < 2048; i += 512) ((unsigned*)sh_ax)[i] = 0;

  const int u  = cb * 16 + sub;   // B n-col / D col
  const int ba = sub >> 2;        // A-side row -> batch (within mblk)
  const int qa = sub & 3;         // A-side row -> q

  // persistent B fragments [g][ks] and bias vectors (C-operand per gate)
  FragU Bf[32];
  FragU Bx[4];
  f32x4 bvv[4];
  {
    const float* Cc[4] = {uhr, uhi, uhj, uhk};
    const float* Xc[4] = {wxr, wxi, wxj, wxk};
    #pragma unroll
    for (int g = 0; g < 4; ++g) {
      #pragma unroll
      for (int ks = 0; ks < 8; ++ks) {
        const int d  = ks >> 1;
        const int pp = (ks & 1) * 32 + quad * 8;
        const float* src = Cc[d] + (size_t)((layer * 4 + g) * 64 + pp) * 64 + u;
        FragU f;
        #pragma unroll
        for (int j = 0; j < 8; ++j) f.v[j] = (short)f2bf(src[j * 64]);
        Bf[g * 8 + ks] = f;
      }
      FragU fx; fx.w[0] = 0; fx.w[1] = 0; fx.w[2] = 0; fx.w[3] = 0;
      if (quad == 0) {
        unsigned e0 = f2bf(Xc[0][(layer * 4 + g) * 64 + u]);
        unsigned e1 = f2bf(Xc[1][(layer * 4 + g) * 64 + u]);
        unsigned e2 = f2bf(Xc[2][(layer * 4 + g) * 64 + u]);
        unsigned e3 = f2bf(Xc[3][(layer * 4 + g) * 64 + u]);
        fx.w[0] = e0 | (e1 << 16);
        fx.w[1] = e2 | (e3 << 16);
      }
      Bx[g] = fx;
      f32x4 bv;
      #pragma unroll
      for (int r = 0; r < 4; ++r) bv[r] = wb[g * 256 + r * 64 + u];
      bvv[g] = bv;
    }
  }
  // A-read byte offsets: sign baked via +/-h copy select, batch = mblk*4+ba
  int aoff[8];
  #pragma unroll
  for (int ks = 0; ks < 8; ++ks) {
    const int d = ks >> 1;
    const int a = qa ^ d;
    const bool neg = (QSIGN_MASK >> (a * 4 + qa)) & 1;
    aoff[ks] = (neg ? 4352 : 0) + (mblk * 4 + ba) * 544
             + ((a * 64 + (ks & 1) * 32 + quad * 8) << 1);
  }

  // wave1 Ax-builder constants (lanes 0-31: tb=lane>>4, ba_=(lane>>2)&3, qa_=lane&3)
  const int tb   = (lane >> 4) & 1;          // target mblk
  const int babs = tb * 4 + ((lane >> 2) & 3);
  unsigned sel0, sel1, sm01, sm23;
  {
    const int qa_ = lane & 3;
    const int a0 = qa_ ^ 0, a1 = qa_ ^ 1, a2 = qa_ ^ 2, a3 = qa_ ^ 3;
    sel0 = (unsigned)(2*a0) | ((unsigned)(2*a0+1) << 8)
         | ((unsigned)(2*a1) << 16) | ((unsigned)(2*a1+1) << 24);
    sel1 = (unsigned)(2*a2) | ((unsigned)(2*a2+1) << 8)
         | ((unsigned)(2*a3) << 16) | ((unsigned)(2*a3+1) << 24);
    unsigned s0_ = ((QSIGN_MASK >> (a0*4+qa_)) & 1) ? 0x8000u : 0u;
    unsigned s1_ = ((QSIGN_MASK >> (a1*4+qa_)) & 1) ? 0x8000u : 0u;
    unsigned s2_ = ((QSIGN_MASK >> (a2*4+qa_)) & 1) ? 0x8000u : 0u;
    unsigned s3_ = ((QSIGN_MASK >> (a3*4+qa_)) & 1) ? 0x8000u : 0u;
    sm01 = s0_ | (s1_ << 16);
    sm23 = s2_ | (s3_ << 16);
  }

  // projection A-fragments (waves 2 and 7): A[m=f][k] = fw[k][f], rows 4-15 zero
  FragU Afp[4];
  f32x4 pbias = {0.f, 0.f, 0.f, 0.f};
  const int bl = sub & 7;   // B-side col -> batch (dup for sub>=8, unused outputs)
  if (wv == 2 || wv == 7) {
    const int ksb = (wv == 2) ? 0 : 4;
    #pragma unroll
    for (int kk = 0; kk < 4; ++kk) {
      FragU f;
      #pragma unroll
      for (int j = 0; j < 8; ++j) {
        const int k = (ksb + kk) * 32 + quad * 8 + j;
        f.v[j] = (sub < 4) ? (short)f2bf(fw[k * 4 + sub]) : (short)0;
      }
      Afp[kk] = f;
    }
    if (wv == 2) { f32x4 pb = {fb[0], fb[1], fb[2], fb[3]}; pbias = pb; }
  }
  const f32x4 zq = {0.f, 0.f, 0.f, 0.f};

  float cs[4] = {0.f, 0.f, 0.f, 0.f};
  f32x4 preg = zq;
  float4 xnext = make_float4(0.f, 0.f, 0.f, 0.f);
  unsigned long long vnext = 0ull;

  BAR();   // LDS memset visible

  // wave1 prologue: build Ax entries 0..2 (both mblks); hold entry 3's raw value
  if (wv == 1) {
    if (role == 0) {
      if (lane < 32) {
        #pragma unroll
        for (int e = 0; e < 3; ++e) {
          float4 xv = *(const float4*)(x_in + (size_t)((bg0 + babs) * T_ + e) * F_);
          unsigned lo = f2bf(xv.x) | (f2bf(xv.y) << 16);
          unsigned hi = f2bf(xv.z) | (f2bf(xv.w) << 16);
          unsigned w0 = __builtin_amdgcn_perm(hi, lo, sel0) ^ sm01;
          unsigned w1 = __builtin_amdgcn_perm(hi, lo, sel1) ^ sm23;
          *(unsigned long long*)&sh_ax[e][tb][lane & 15][0] =
              ((unsigned long long)w1 << 32) | w0;
        }
        xnext = *(const float4*)(x_in + (size_t)((bg0 + babs) * T_ + 3) * F_);
      }
    } else {
      for (int e = 0; e < 3; ++e) {
        unsigned long long vq = (lane < 32)
            ? __hip_atomic_load(&g_inter_q[e][bg0 + babs], __ATOMIC_RELAXED,
                                __HIP_MEMORY_SCOPE_AGENT) : 1ull;
        while (__any(vq == 0ull)) {
          __builtin_amdgcn_s_sleep(8);
          vq = (lane < 32)
              ? __hip_atomic_load(&g_inter_q[e][bg0 + babs], __ATOMIC_RELAXED,
                                  __HIP_MEMORY_SCOPE_AGENT) : 1ull;
        }
        if (lane < 32) {
          unsigned lo = (unsigned)vq, hi = (unsigned)(vq >> 32);
          unsigned w0 = __builtin_amdgcn_perm(hi, lo, sel0) ^ sm01;
          unsigned w1 = __builtin_amdgcn_perm(hi, lo, sel1) ^ sm23;
          *(unsigned long long*)&sh_ax[e][tb][lane & 15][0] =
              ((unsigned long long)w1 << 32) | w0;
        }
      }
      if (lane < 32)
        vnext = __hip_atomic_load(&g_inter_q[3][bg0 + babs], __ATOMIC_RELAXED,
                                  __HIP_MEMORY_SCOPE_AGENT);
    }
  }
  BAR();

  const char* hbB = (const char*)sh_h;
  for (int s = 0; s <= T_ + 1; ++s) {
    const char* hp = hbB + ((s + 1) & 1) * 8704;   // h[s-1] buffer (plain copy at +0)

    // ---- wave2: finish+publish entry s-2, then new proj partial (ks 0-3) ----
    if (wv == 2) {
      const bool fin = (role == 0) ? (s >= 2) : (s == T_ + 1);
      if (fin && lane < 8) {
        f32x4 pq = *(const f32x4*)&sh_pp[(s + 1) & 1][lane][0];  // wave7 @ s-1
        float p0 = preg[0] + pq[0], p1 = preg[1] + pq[1];
        float p2 = preg[2] + pq[2], p3 = preg[3] + pq[3];
        float inv = 1.f / fmaxf(sqrtf(p0*p0 + p1*p1 + p2*p2 + p3*p3), 1e-12f);
        p0 *= inv; p1 *= inv; p2 *= inv; p3 *= inv;
        if (role == 0) {
          unsigned plo, phi;
          asm("v_cvt_pk_bf16_f32 %0, %1, %2" : "=v"(plo) : "v"(p0), "v"(p1));
          asm("v_cvt_pk_bf16_f32 %0, %1, %2" : "=v"(phi) : "v"(p2), "v"(p3));
          __hip_atomic_store(&g_inter_q[s - 2][bg0 + lane],
                             ((unsigned long long)phi << 32) | plo,
                             __ATOMIC_RELAXED, __HIP_MEMORY_SCOPE_AGENT);
        } else {
          *(float4*)(out_final + (bg0 + lane) * F_) = make_float4(p0, p1, p2, p3);
        }
      }
      const bool dop = (role == 0) ? (s >= 1 && s <= T_) : (s == T_);
      if (dop) {
        FragU Bh;
        Bh.u = *(const uint4*)(hp + bl * 544 + ((0 * 32 + quad * 8) << 1));
        f32x4 pa = __builtin_amdgcn_mfma_f32_16x16x32_bf16(Afp[0].v, Bh.v, pbias, 0, 0, 0);
        #pragma unroll
        for (int kk = 1; kk < 4; ++kk) {
          Bh.u = *(const uint4*)(hp + bl * 544 + ((kk * 32 + quad * 8) << 1));
          pa = __builtin_amdgcn_mfma_f32_16x16x32_bf16(Afp[kk].v, Bh.v, pa, 0, 0, 0);
        }
        preg = pa;
      }
    }

    // ---- wave7: proj partial ks 4-7 of h[s-1] -> sh_pp[s&1] ----
    if (wv == 7) {
      const bool dop = (role == 0) ? (s >= 1 && s <= T_) : (s == T_);
      if (dop) {
        FragU Bh;
        Bh.u = *(const uint4*)(hp + bl * 544 + ((4 * 32 + quad * 8) << 1));
        f32x4 pb = __builtin_amdgcn_mfma_f32_16x16x32_bf16(Afp[0].v, Bh.v, zq, 0, 0, 0);
        #pragma unroll
        for (int kk = 1; kk < 4; ++kk) {
          Bh.u = *(const uint4*)(hp + bl * 544 + (((4 + kk) * 32 + quad * 8) << 1));
          pb = __builtin_amdgcn_mfma_f32_16x16x32_bf16(Afp[kk].v, Bh.v, pb, 0, 0, 0);
        }
        if (lane < 8) *(f32x4*)&sh_pp[s & 1][lane][0] = pb;
      }
    }

    // ---- LSTM step: h[s] (all 8 waves) ----
    if (s < T_) {
      FragU Ax;
      Ax.u = *(const uint4*)&sh_ax[s & 3][mblk][lane][0];   // pre-built, signs baked
      f32x4 acc0 = __builtin_amdgcn_mfma_f32_16x16x32_bf16(Ax.v, Bx[0].v, bvv[0], 0, 0, 0);
      f32x4 acc1 = __builtin_amdgcn_mfma_f32_16x16x32_bf16(Ax.v, Bx[1].v, bvv[1], 0, 0, 0);
      f32x4 acc2 = __builtin_amdgcn_mfma_f32_16x16x32_bf16(Ax.v, Bx[2].v, bvv[2], 0, 0, 0);
      f32x4 acc3 = __builtin_amdgcn_mfma_f32_16x16x32_bf16(Ax.v, Bx[3].v, bvv[3], 0, 0, 0);
      #pragma unroll
      for (int ks = 0; ks < 8; ++ks) {
        FragU A;
        A.u = *(const uint4*)(hp + aoff[ks]);   // sign pre-baked via copy select
        acc0 = __builtin_amdgcn_mfma_f32_16x16x32_bf16(A.v, Bf[0 * 8 + ks].v, acc0, 0, 0, 0);
        acc1 = __builtin_amdgcn_mfma_f32_16x16x32_bf16(A.v, Bf[1 * 8 + ks].v, acc1, 0, 0, 0);
        acc2 = __builtin_amdgcn_mfma_f32_16x16x32_bf16(A.v, Bf[2 * 8 + ks].v, acc2, 0, 0, 0);
        acc3 = __builtin_amdgcn_mfma_f32_16x16x32_bf16(A.v, Bf[3 * 8 + ks].v, acc3, 0, 0, 0);
      }
      float hv0, hv1, hv2, hv3;
      {
        float fg, ig, og, cv;
        fg = fast_sigmoid(acc0[0]); ig = fast_sigmoid(acc1[0]);
        og = fast_sigmoid(acc2[0]); cv = fast_tanh(acc3[0]);
        cs[0] = ig * cv + fg * cs[0]; hv0 = og * fast_tanh(cs[0]);
        fg = fast_sigmoid(acc0[1]); ig = fast_sigmoid(acc1[1]);
        og = fast_sigmoid(acc2[1]); cv = fast_tanh(acc3[1]);
        cs[1] = ig * cv + fg * cs[1]; hv1 = og * fast_tanh(cs[1]);
        fg = fast_sigmoid(acc0[2]); ig = fast_sigmoid(acc1[2]);
        og = fast_sigmoid(acc2[2]); cv = fast_tanh(acc3[2]);
        cs[2] = ig * cv + fg * cs[2]; hv2 = og * fast_tanh(cs[2]);
        fg = fast_sigmoid(acc0[3]); ig = fast_sigmoid(acc1[3]);
        og = fast_sigmoid(acc2[3]); cv = fast_tanh(acc3[3]);
        cs[3] = ig * cv + fg * cs[3]; hv3 = og * fast_tanh(cs[3]);
      }
      unsigned w01, w23;
      asm("v_cvt_pk_bf16_f32 %0, %1, %2" : "=v"(w01) : "v"(hv0), "v"(hv1));
      asm("v_cvt_pk_bf16_f32 %0, %1, %2" : "=v"(w23) : "v"(hv2), "v"(hv3));
      const unsigned n01 = w01 ^ 0x80008000u;
      const unsigned n23 = w23 ^ 0x80008000u;
      char* hw = (char*)sh_h + (s & 1) * 8704 + (mblk * 4 + quad) * 544;
      const int ub = u << 1;
      *(unsigned short*)(hw + ub)              = (unsigned short)w01;
      *(unsigned short*)(hw + 128 + ub)        = (unsigned short)(w01 >> 16);
      *(unsigned short*)(hw + 256 + ub)        = (unsigned short)w23;
      *(unsigned short*)(hw + 384 + ub)        = (unsigned short)(w23 >> 16);
      *(unsigned short*)(hw + 4352 + ub)       = (unsigned short)n01;
      *(unsigned short*)(hw + 4352 + 128 + ub) = (unsigned short)(n01 >> 16);
      *(unsigned short*)(hw + 4352 + 256 + ub) = (unsigned short)n23;
      *(unsigned short*)(hw + 4352 + 384 + ub) = (unsigned short)(n23 >> 16);
    }

    // ---- wave1: staging. Build entry s+3 from held value; issue load for s+4 ----
    if (wv == 1) {
      const int e0 = s + 3;
      if (e0 < T_) {
        if (role == 0) {
          if (lane < 32) {
            unsigned lo = f2bf(xnext.x) | (f2bf(xnext.y) << 16);
            unsigned hi = f2bf(xnext.z) | (f2bf(xnext.w) << 16);
            unsigned w0 = __builtin_amdgcn_perm(hi, lo, sel0) ^ sm01;
            unsigned w1 = __builtin_amdgcn_perm(hi, lo, sel1) ^ sm23;
            *(unsigned long long*)&sh_ax[e0 & 3][tb][lane & 15][0] =
                ((unsigned long long)w1 << 32) | w0;
            if (e0 + 1 < T_)
              xnext = *(const float4*)(x_in + (size_t)((bg0 + babs) * T_ + e0 + 1) * F_);
          }
        } else {
          unsigned long long vq = (lane < 32) ? vnext : 1ull;
          while (__any(vq == 0ull)) {
            __builtin_amdgcn_s_sleep(2);
            vq = (lane < 32)
                ? __hip_atomic_load(&g_inter_q[e0][bg0 + babs], __ATOMIC_RELAXED,
                                    __HIP_MEMORY_SCOPE_AGENT) : 1ull;
          }
          if (lane < 32) {
            unsigned lo = (unsigned)vq, hi = (unsigned)(vq >> 32);
            unsigned w0 = __builtin_amdgcn_perm(hi, lo, sel0) ^ sm01;
            unsigned w1 = __builtin_amdgcn_perm(hi, lo, sel1) ^ sm23;
            *(unsigned long long*)&sh_ax[e0 & 3][tb][lane & 15][0] =
                ((unsigned long long)w1 << 32) | w0;
            if (e0 + 1 < T_)
              vnext = __hip_atomic_load(&g_inter_q[e0 + 1][bg0 + babs], __ATOMIC_RELAXED,
                                        __HIP_MEMORY_SCOPE_AGENT);
          }
        }
      }
    }
    BAR();
  }
}

extern "C" void kernel_launch(void* const* d_in, const int* in_sizes, int n_in,
                              void* d_out, int out_size, void* d_ws, size_t ws_size,
                              hipStream_t stream) {
  const float* x   = (const float*)d_in[0];
  const float* wxr = (const float*)d_in[1];
  const float* wxi = (const float*)d_in[2];
  const float* wxj = (const float*)d_in[3];
  const float* wxk = (const float*)d_in[4];
  const float* wxb = (const float*)d_in[5];
  const float* uhr = (const float*)d_in[6];
  const float* uhi = (const float*)d_in[7];
  const float* uhj = (const float*)d_in[8];
  const float* uhk = (const float*)d_in[9];
  const float* fcw = (const float*)d_in[10];
  const float* fcb = (const float*)d_in[11];
  float* out = (float*)d_out;

  zero_inter<<<dim3(T_ * B_ / 256), dim3(256), 0, stream>>>();
  qlstm_fused<<<dim3(32), dim3(512), 0, stream>>>(
      x, uhr, uhi, uhj, uhk, wxr, wxi, wxj, wxk, wxb, fcw, fcb, out);
}

// Round 6
// 546.616 us; speedup vs baseline: 2.7986x; 2.7986x over previous
//
#include <hip/hip_runtime.h>

#define L_ 2
#define T_ 512
#define B_ 128
#define F_ 4
#define H_ 256
#define QSIGN_MASK 0x5390

typedef __attribute__((ext_vector_type(8))) short short8;
typedef __attribute__((ext_vector_type(4))) float f32x4;

// Mailbox: layer-0 normalized output, bf16x4 packed per (t,b); norm-1 => nonzero.
__device__ unsigned long long g_inter_q[T_][B_];

__global__ void zero_inter() {
  ((unsigned long long*)g_inter_q)[blockIdx.x * 256 + threadIdx.x] = 0ull;
}

__device__ __forceinline__ unsigned f2bf(float f) {
  unsigned u = __float_as_uint(f);
  return (u + 0x7fff + ((u >> 16) & 1)) >> 16;
}
// R6: v_rcp_f32-based gates. The old 1.f/x forms compiled to the exact-division
// sequence (~8-10 instrs each); 20 gate evals/lane/step made that ~40% of the
// step's VALU. v_rcp is ~1 ulp — far below bf16-h rounding and the 0.0039 tol.
__device__ __forceinline__ float fast_sigmoid(float x) {
  return __builtin_amdgcn_rcpf(1.f + __expf(-x));
}
__device__ __forceinline__ float fast_tanh(float x) {
  float a = fabsf(x), e = __expf(2.f * a);
  return copysignf(1.f - 2.f * __builtin_amdgcn_rcpf(e + 1.f), x);
}
// RNE pack, identical rounding to f2bf, 2 instrs instead of ~16.
__device__ __forceinline__ unsigned long long pack4bf(float a, float b, float c, float d) {
  unsigned lo, hi;
  asm("v_cvt_pk_bf16_f32 %0, %1, %2" : "=v"(lo) : "v"(a), "v"(b));
  asm("v_cvt_pk_bf16_f32 %0, %1, %2" : "=v"(hi) : "v"(c), "v"(d));
  return ((unsigned long long)hi << 32) | lo;
}

union FragU { short8 v; uint4 u; unsigned w[4]; };

// Grid = 64 WGs x 320 threads (5 waves). blockIdx<32: layer-0 producer; else layer-1.
// R0 structure (session-best, 714us verified) with ONLY local math swaps:
// rcp-gates, rsq-norm, cvt_pk packing, bias via MFMA C-operand.
// Compute waves 0-3: wave w owns cols u in [16w,16w+16). MFMA M rows = b*4+q
// (b=quad, q=reg in C/D), N = u16, one accumulator set per gate -> each lane holds
// all (q,g) for its (b,u): LSTM update fully in-lane, ZERO cross-lane ops, one
// barrier/step. Bias preloaded via C-operand; x-term = 1 MFMA per gate.
// Helper wave 4: projection via MFMA (P^T[f][b] = fw^T . h): lanes 0-3 get all 4
// components in-reg (no shuffles), publish mailbox every 2 steps (halves drains);
// x prefetch depth 2 into ring-4 sh_x.
__launch_bounds__(320, 1)
__global__ void qlstm_fused(const float* __restrict__ x_in,
                            const float* __restrict__ uhr, const float* __restrict__ uhi,
                            const float* __restrict__ uhj, const float* __restrict__ uhk,
                            const float* __restrict__ wxr, const float* __restrict__ wxi,
                            const float* __restrict__ wxj, const float* __restrict__ wxk,
                            const float* __restrict__ wxb_all,
                            const float* __restrict__ fcw_all, const float* __restrict__ fcb_all,
                            float* __restrict__ out_final)
{
  __shared__ __align__(16) unsigned short sh_h[2][4][272];  // double-buffered h (bf16)
  __shared__ unsigned long long sh_x[4][4];                 // ring-4 x, bf16x4 packed

  const int t     = threadIdx.x;
  const int role  = blockIdx.x >> 5;
  const int bg    = blockIdx.x & 31;
  const int bg0   = bg * 4;
  const int layer = role;
  const int wv    = t >> 6;
  const int lane  = t & 63;
  const int quad  = lane >> 4;
  const int sub   = lane & 15;

  const float* wb = wxb_all + layer * 4 * H_;
  const float* fw = fcw_all + layer * H_ * F_;
  const float* fb = fcb_all + layer * F_;

  for (int i = t; i < 2176; i += 320) ((unsigned short*)sh_h)[i] = 0;

  if (wv < 4) {
    // ================= COMPUTE WAVES =================
    const int u  = wv * 16 + sub;   // B n-col / D col
    const int ba = sub >> 2;        // A-side row -> batch
    const int qa = sub & 3;         // A-side row -> q

    // persistent B fragments [g][ks]: raw component blocks (d=ks>>1, p-half=ks&1)
    FragU Bf[32];
    FragU Bx[4];
    f32x4 bvv[4];
    {
      const float* Cc[4] = {uhr, uhi, uhj, uhk};
      const float* Xc[4] = {wxr, wxi, wxj, wxk};
      #pragma unroll
      for (int g = 0; g < 4; ++g) {
        #pragma unroll
        for (int ks = 0; ks < 8; ++ks) {
          const int d  = ks >> 1;
          const int pp = (ks & 1) * 32 + quad * 8;
          const float* src = Cc[d] + (size_t)((layer * 4 + g) * 64 + pp) * 64 + u;
          FragU f;
          #pragma unroll
          for (int j = 0; j < 8; ++j) f.v[j] = (short)f2bf(src[j * 64]);
          Bf[g * 8 + ks] = f;
        }
        FragU fx; fx.w[0] = 0; fx.w[1] = 0; fx.w[2] = 0; fx.w[3] = 0;
        if (quad == 0) {
          unsigned e0 = f2bf(Xc[0][(layer * 4 + g) * 64 + u]);
          unsigned e1 = f2bf(Xc[1][(layer * 4 + g) * 64 + u]);
          unsigned e2 = f2bf(Xc[2][(layer * 4 + g) * 64 + u]);
          unsigned e3 = f2bf(Xc[3][(layer * 4 + g) * 64 + u]);
          fx.w[0] = e0 | (e1 << 16);
          fx.w[1] = e2 | (e3 << 16);
        }
        Bx[g] = fx;
        f32x4 bv;
        #pragma unroll
        for (int r = 0; r < 4; ++r) bv[r] = wb[g * 256 + r * 64 + u];
        bvv[g] = bv;
      }
    }
    // sign masks (a = qa^d) and A-read byte offsets
    unsigned smask[4], smx[4];
    int xsh[4], aoff[8];
    #pragma unroll
    for (int d = 0; d < 4; ++d) {
      const int a = qa ^ d;
      const bool neg = (QSIGN_MASK >> (a * 4 + qa)) & 1;
      smask[d] = neg ? 0x80008000u : 0u;
      smx[d]   = neg ? 0x8000u : 0u;
      xsh[d]   = 16 * a;
    }
    #pragma unroll
    for (int ks = 0; ks < 8; ++ks)
      aoff[ks] = ba * 544 + (((qa ^ (ks >> 1)) * 64 + (ks & 1) * 32 + quad * 8) << 1);
    float cs[4] = {0.f, 0.f, 0.f, 0.f};
    __syncthreads();

    const char* hbB = (const char*)sh_h;
    for (int s = 0; s <= T_; ++s) {
      if (s < T_) {
        const char* hp = hbB + ((s + 1) & 1) * 2176;   // h[s-1]
        // x A-frag: k=d (0..3), value = sign(a,q)*x[b][a], a=q^d
        unsigned long long xq = sh_x[s & 3][ba];
        FragU Ax; Ax.w[0] = 0; Ax.w[1] = 0; Ax.w[2] = 0; Ax.w[3] = 0;
        if (quad == 0) {
          unsigned e0 = ((unsigned)(xq >> xsh[0]) & 0xffffu) ^ smx[0];
          unsigned e1 = ((unsigned)(xq >> xsh[1]) & 0xffffu) ^ smx[1];
          unsigned e2 = ((unsigned)(xq >> xsh[2]) & 0xffffu) ^ smx[2];
          unsigned e3 = ((unsigned)(xq >> xsh[3]) & 0xffffu) ^ smx[3];
          Ax.w[0] = e0 | (e1 << 16);
          Ax.w[1] = e2 | (e3 << 16);
        }
        // bias enters as the MFMA C-operand (no acc-init movs)
        f32x4 acc0 = __builtin_amdgcn_mfma_f32_16x16x32_bf16(Ax.v, Bx[0].v, bvv[0], 0, 0, 0);
        f32x4 acc1 = __builtin_amdgcn_mfma_f32_16x16x32_bf16(Ax.v, Bx[1].v, bvv[1], 0, 0, 0);
        f32x4 acc2 = __builtin_amdgcn_mfma_f32_16x16x32_bf16(Ax.v, Bx[2].v, bvv[2], 0, 0, 0);
        f32x4 acc3 = __builtin_amdgcn_mfma_f32_16x16x32_bf16(Ax.v, Bx[3].v, bvv[3], 0, 0, 0);
        #pragma unroll
        for (int ks = 0; ks < 8; ++ks) {
          FragU A;
          A.u = *(const uint4*)(hp + aoff[ks]);
          const unsigned m = smask[ks >> 1];
          A.w[0] ^= m; A.w[1] ^= m; A.w[2] ^= m; A.w[3] ^= m;
          acc0 = __builtin_amdgcn_mfma_f32_16x16x32_bf16(A.v, Bf[0 * 8 + ks].v, acc0, 0, 0, 0);
          acc1 = __builtin_amdgcn_mfma_f32_16x16x32_bf16(A.v, Bf[1 * 8 + ks].v, acc1, 0, 0, 0);
          acc2 = __builtin_amdgcn_mfma_f32_16x16x32_bf16(A.v, Bf[2 * 8 + ks].v, acc2, 0, 0, 0);
          acc3 = __builtin_amdgcn_mfma_f32_16x16x32_bf16(A.v, Bf[3 * 8 + ks].v, acc3, 0, 0, 0);
        }
        // fully in-lane gates: b=quad, c = r*64+u for r=0..3
        float hv0, hv1, hv2, hv3;
        {
          float fg, ig, og, cv;
          fg = fast_sigmoid(acc0[0]); ig = fast_sigmoid(acc1[0]);
          og = fast_sigmoid(acc2[0]); cv = fast_tanh(acc3[0]);
          cs[0] = ig * cv + fg * cs[0]; hv0 = og * fast_tanh(cs[0]);
          fg = fast_sigmoid(acc0[1]); ig = fast_sigmoid(acc1[1]);
          og = fast_sigmoid(acc2[1]); cv = fast_tanh(acc3[1]);
          cs[1] = ig * cv + fg * cs[1]; hv1 = og * fast_tanh(cs[1]);
          fg = fast_sigmoid(acc0[2]); ig = fast_sigmoid(acc1[2]);
          og = fast_sigmoid(acc2[2]); cv = fast_tanh(acc3[2]);
          cs[2] = ig * cv + fg * cs[2]; hv2 = og * fast_tanh(cs[2]);
          fg = fast_sigmoid(acc0[3]); ig = fast_sigmoid(acc1[3]);
          og = fast_sigmoid(acc2[3]); cv = fast_tanh(acc3[3]);
          cs[3] = ig * cv + fg * cs[3]; hv3 = og * fast_tanh(cs[3]);
        }
        unsigned w01, w23;
        asm("v_cvt_pk_bf16_f32 %0, %1, %2" : "=v"(w01) : "v"(hv0), "v"(hv1));
        asm("v_cvt_pk_bf16_f32 %0, %1, %2" : "=v"(w23) : "v"(hv2), "v"(hv3));
        char* hw = (char*)sh_h + (s & 1) * 2176 + quad * 544;
        const int ub = u << 1;
        *(unsigned short*)(hw + ub)       = (unsigned short)w01;
        *(unsigned short*)(hw + 128 + ub) = (unsigned short)(w01 >> 16);
        *(unsigned short*)(hw + 256 + ub) = (unsigned short)w23;
        *(unsigned short*)(hw + 384 + ub) = (unsigned short)(w23 >> 16);
      }
      __syncthreads();
    }
  } else {
    // ================= HELPER WAVE =================
    // fw^T A-frags: A[m=f][k] = fw[k][f], rows 4-15 zero
    FragU Af[8];
    #pragma unroll
    for (int ks = 0; ks < 8; ++ks) {
      FragU f;
      #pragma unroll
      for (int j = 0; j < 8; ++j) {
        const int k = ks * 32 + quad * 8 + j;
        f.v[j] = (sub < 4) ? (short)f2bf(fw[k * 4 + sub]) : (short)0;
      }
      Af[ks] = f;
    }
    const float fb0 = fb[0], fb1 = fb[1], fb2 = fb[2], fb3 = fb[3];
    const int bl = sub & 3;   // B-side col (batch), clamped for lanes >= 4

    // prologue: x slots 0,1
    if (lane < 4) {
      #pragma unroll
      for (int s0 = 0; s0 < 2; ++s0) {
        if (role == 0) {
          float4 xv = *(const float4*)(x_in + (size_t)((bg0 + lane) * T_ + s0) * F_);
          sh_x[s0][lane] = pack4bf(xv.x, xv.y, xv.z, xv.w);
        } else {
          unsigned long long v;
          while ((v = __hip_atomic_load(&g_inter_q[s0][bg0 + lane], __ATOMIC_RELAXED,
                                        __HIP_MEMORY_SCOPE_AGENT)) == 0ull)
            __builtin_amdgcn_s_sleep(1);
          sh_x[s0][lane] = v;
        }
      }
    }
    unsigned long long heldq = 0ull;
    __syncthreads();

    for (int s = 0; s <= T_; ++s) {
      const bool doproj = (s >= 1) && (role == 0 || s == T_);
      if (doproj) {
        const char* hp = (const char*)sh_h + ((s + 1) & 1) * 2176;  // h[s-1]
        f32x4 pa = {fb0, fb1, fb2, fb3};
        #pragma unroll
        for (int ks = 0; ks < 8; ++ks) {
          FragU Bh;
          Bh.u = *(const uint4*)(hp + bl * 544 + ((ks * 32 + quad * 8) << 1));
          pa = __builtin_amdgcn_mfma_f32_16x16x32_bf16(Af[ks].v, Bh.v, pa, 0, 0, 0);
        }
        if (lane < 4) {   // quad==0, sub<4: all 4 components in-reg, batch = lane
          float p0 = pa[0], p1 = pa[1], p2 = pa[2], p3 = pa[3];
          float inv = __builtin_amdgcn_rsqf(
              fmaxf(p0*p0 + p1*p1 + p2*p2 + p3*p3, 1e-24f));
          p0 *= inv; p1 *= inv; p2 *= inv; p3 *= inv;
          if (role == 0) {
            unsigned long long qw = pack4bf(p0, p1, p2, p3);
            if (s & 1) {
              heldq = qw;              // idx s-1 held one step
            } else {                   // publish pair (s-2, s-1): one drain per 2 steps
              __hip_atomic_store(&g_inter_q[s - 2][bg0 + lane], heldq,
                                 __ATOMIC_RELAXED, __HIP_MEMORY_SCOPE_AGENT);
              __hip_atomic_store(&g_inter_q[s - 1][bg0 + lane], qw,
                                 __ATOMIC_RELAXED, __HIP_MEMORY_SCOPE_AGENT);
            }
          } else {                     // consumer, s == T: final output
            *(float4*)(out_final + (bg0 + lane) * F_) = make_float4(p0, p1, p2, p3);
          }
        }
      }
      if (lane < 4 && s + 2 < T_) {
        const int slot = (s + 2) & 3;
        if (role == 0) {
          float4 xv = *(const float4*)(x_in + (size_t)((bg0 + lane) * T_ + s + 2) * F_);
          sh_x[slot][lane] = pack4bf(xv.x, xv.y, xv.z, xv.w);
        } else {
          unsigned long long v;
          while ((v = __hip_atomic_load(&g_inter_q[s + 2][bg0 + lane], __ATOMIC_RELAXED,
                                        __HIP_MEMORY_SCOPE_AGENT)) == 0ull)
            __builtin_amdgcn_s_sleep(1);
          sh_x[slot][lane] = v;
        }
      }
      __syncthreads();
    }
  }
}

extern "C" void kernel_launch(void* const* d_in, const int* in_sizes, int n_in,
                              void* d_out, int out_size, void* d_ws, size_t ws_size,
                              hipStream_t stream) {
  const float* x   = (const float*)d_in[0];
  const float* wxr = (const float*)d_in[1];
  const float* wxi = (const float*)d_in[2];
  const float* wxj = (const float*)d_in[3];
  const float* wxk = (const float*)d_in[4];
  const float* wxb = (const float*)d_in[5];
  const float* uhr = (const float*)d_in[6];
  const float* uhi = (const float*)d_in[7];
  const float* uhj = (const float*)d_in[8];
  const float* uhk = (const float*)d_in[9];
  const float* fcw = (const float*)d_in[10];
  const float* fcb = (const float*)d_in[11];
  float* out = (float*)d_out;

  zero_inter<<<dim3(T_ * B_ / 256), dim3(256), 0, stream>>>();
  qlstm_fused<<<dim3(64), dim3(320), 0, stream>>>(
      x, uhr, uhi, uhj, uhk, wxr, wxi, wxj, wxk, wxb, fcw, fcb, out);
}